// Round 6
// baseline (743.554 us; speedup 1.0000x reference)
//
#include <hip/hip_runtime.h>
#include <math.h>

#define B_    2048
#define S_    134
#define E_    256
#define H_    1024
#define T_    5
#define KK_   6
#define NROWS (B_*T_)          // 10240
#define R_    16               // rows per block
#define NT_   512              // threads per block (8 waves)
#define NBLK  (NROWS/R_)       // 640

// output layout (flat concat in return order)
#define OFF_LOGITS 1
#define OFF_SCORES (OFF_LOGITS + NROWS*12)   // 122881
#define OFF_SEL    (OFF_SCORES + NROWS*6)    // 184321
#define OFF_LPK    (OFF_SEL + NROWS*2)       // 204801

// One decoder phase: GEMM1 (x@w1+b1) -> LayerNorm -> ReLU -> GEMM2 ([x,h]@w2+b2)
// R=16 rows / 512 threads / 2 cols per thread:
//   - w1 is streamed ONCE per block for 16 rows (2x reuse vs R=8) -> w1 L2
//     traffic halves (640 blocks x 2 MB), and each w1 byte feeds 4 FMAs.
//   - acc[16][2] = 32 VGPRs (same pressure as the proven acc[8][4]).
//   - LN cross-wave reduction overlays hs[8][0..255] (dead until LN-apply of
//     rows 8..15); fold is split into two row-halves so only mu/rs[8] (16
//     regs) are live at once. Barrier after BOTH folds, before hs[8..15]
//     writes clobber the aux region.
// LDS = 64K (hs) + 16K (xs) = 81920 B exactly -> 2 blocks/CU = 16 waves/CU.
// Spill history: (256,4) made the allocator jump to the 64-VGPR bucket and
// spill (rounds 1/4); keep peak live ~70 so even an aggressive bucket fits.
template<int NOUT>
__device__ __forceinline__ void decoder_phase(
    const float (*xs)[E_],
    const float* __restrict__ w1, const float* __restrict__ b1,
    const float* __restrict__ ga, const float* __restrict__ be,
    const float* __restrict__ w2, const float* __restrict__ b2,
    float (*hs)[H_], float* aux,            // aux == &hs[8][0], 256 floats
    float* __restrict__ gout, int g0, int tid)
{
    const int wave = tid >> 6;   // 0..7
    const int lane = tid & 63;
    const int j0   = tid * 2;    // this thread's column pair in [0,1024)

    // ---- GEMM1: acc[r][c] = xs[r][:] . w1[:, j0+c] ----
    float acc[R_][2];
#pragma unroll
    for (int r = 0; r < R_; ++r) { acc[r][0] = 0.f; acc[r][1] = 0.f; }

    for (int k0 = 0; k0 < E_; k0 += 8) {
        // 8 coalesced float2 loads of w1 in flight (16 VGPRs)
        float2 w[8];
#pragma unroll
        for (int kk = 0; kk < 8; ++kk)
            w[kk] = *(const float2*)(w1 + (size_t)(k0 + kk)*H_ + j0);
#pragma unroll
        for (int r = 0; r < R_; ++r) {
            float4 xa = *(const float4*)&xs[r][k0];     // wave-uniform -> LDS broadcast
            float4 xb = *(const float4*)&xs[r][k0+4];
            acc[r][0] += xa.x*w[0].x; acc[r][1] += xa.x*w[0].y;
            acc[r][0] += xa.y*w[1].x; acc[r][1] += xa.y*w[1].y;
            acc[r][0] += xa.z*w[2].x; acc[r][1] += xa.z*w[2].y;
            acc[r][0] += xa.w*w[3].x; acc[r][1] += xa.w*w[3].y;
            acc[r][0] += xb.x*w[4].x; acc[r][1] += xb.x*w[4].y;
            acc[r][0] += xb.y*w[5].x; acc[r][1] += xb.y*w[5].y;
            acc[r][0] += xb.z*w[6].x; acc[r][1] += xb.z*w[6].y;
            acc[r][0] += xb.w*w[7].x; acc[r][1] += xb.w*w[7].y;
        }
    }

    // bias
    {
        float2 bv = *(const float2*)(b1 + j0);
#pragma unroll
        for (int r = 0; r < R_; ++r) { acc[r][0] += bv.x; acc[r][1] += bv.y; }
    }

    // ---- LayerNorm stats: per-row sum / sumsq across 1024 cols ----
#pragma unroll
    for (int r = 0; r < R_; ++r) {
        float s  = acc[r][0] + acc[r][1];
        float ss = acc[r][0]*acc[r][0] + acc[r][1]*acc[r][1];
#pragma unroll
        for (int off = 32; off > 0; off >>= 1) {
            s  += __shfl_xor(s,  off, 64);
            ss += __shfl_xor(ss, off, 64);
        }
        if (lane == 0) { aux[r*16 + wave*2 + 0] = s; aux[r*16 + wave*2 + 1] = ss; }
    }
    __syncthreads();

    const float2 gv = *(const float2*)(ga + j0);
    const float2 bv = *(const float2*)(be + j0);

    // fold rows 0..7 (reads aux = hs[8][0..127])
    float mu0[8], rs0[8];
#pragma unroll
    for (int r = 0; r < 8; ++r) {
        float s = 0.f, ss = 0.f;
#pragma unroll
        for (int w8 = 0; w8 < 8; ++w8) {
            float2 pr = *(const float2*)&aux[r*16 + w8*2];
            s += pr.x; ss += pr.y;
        }
        float m = s * (1.0f / H_);
        mu0[r] = m;
        rs0[r] = rsqrtf(ss * (1.0f / H_) - m*m + 1e-5f);
    }
    // apply rows 0..7 (writes hs[0..7] -- disjoint from aux region hs[8])
#pragma unroll
    for (int r = 0; r < 8; ++r) {
        float2 hv;
        hv.x = gv.x * ((acc[r][0] - mu0[r]) * rs0[r]) + bv.x;
        hv.y = gv.y * ((acc[r][1] - mu0[r]) * rs0[r]) + bv.y;
        hv.x = hv.x > 0.f ? hv.x : 0.f;
        hv.y = hv.y > 0.f ? hv.y : 0.f;
        *(float2*)&hs[r][j0] = hv;
    }
    // fold rows 8..15 (reads aux = hs[8][128..255], not yet clobbered)
    float mu1[8], rs1[8];
#pragma unroll
    for (int r = 0; r < 8; ++r) {
        float s = 0.f, ss = 0.f;
#pragma unroll
        for (int w8 = 0; w8 < 8; ++w8) {
            float2 pr = *(const float2*)&aux[(r+8)*16 + w8*2];
            s += pr.x; ss += pr.y;
        }
        float m = s * (1.0f / H_);
        mu1[r] = m;
        rs1[r] = rsqrtf(ss * (1.0f / H_) - m*m + 1e-5f);
    }
    __syncthreads();   // ALL folds done before hs[8..15] writes clobber aux

    // apply rows 8..15
#pragma unroll
    for (int r = 0; r < 8; ++r) {
        float2 hv;
        hv.x = gv.x * ((acc[r+8][0] - mu1[r]) * rs1[r]) + bv.x;
        hv.y = gv.y * ((acc[r+8][1] - mu1[r]) * rs1[r]) + bv.y;
        hv.x = hv.x > 0.f ? hv.x : 0.f;
        hv.y = hv.y > 0.f ? hv.y : 0.f;
        *(float2*)&hs[r+8][j0] = hv;
    }
    __syncthreads();

    // ---- GEMM2: out[r][n] = [x,h][r] . w2[:, n] + b2[n] ----
    // 8 waves x 2 rows each; lane owns j in [20*lane, 20*lane+20)
    float p[2][NOUT];
#pragma unroll
    for (int rr = 0; rr < 2; ++rr)
#pragma unroll
        for (int n = 0; n < NOUT; ++n) p[rr][n] = 0.f;

    const int jbase = lane * 20;
#pragma unroll
    for (int jj = 0; jj < 20; ++jj) {
        const int j = jbase + jj;
        float w2r[NOUT];
#pragma unroll
        for (int n = 0; n < NOUT; ++n) w2r[n] = w2[(size_t)j*NOUT + n];
#pragma unroll
        for (int rr = 0; rr < 2; ++rr) {
            const int r = wave*2 + rr;
            float v = (j < E_) ? xs[r][j] : hs[r][j - E_];
#pragma unroll
            for (int n = 0; n < NOUT; ++n) p[rr][n] += v * w2r[n];
        }
    }
    // butterfly reduce across the wave
#pragma unroll
    for (int rr = 0; rr < 2; ++rr)
#pragma unroll
        for (int n = 0; n < NOUT; ++n)
#pragma unroll
            for (int off = 32; off > 0; off >>= 1)
                p[rr][n] += __shfl_xor(p[rr][n], off, 64);

    if (lane == 0) {
#pragma unroll
        for (int rr = 0; rr < 2; ++rr) {
            const int g = g0 + wave*2 + rr;
#pragma unroll
            for (int n = 0; n < NOUT; ++n)
                gout[(size_t)g*NOUT + n] = p[rr][n] + b2[n];
        }
    }
    __syncthreads();   // next phase's aux write must wait for all GEMM2 hs reads
}

__global__ __launch_bounds__(NT_, 2)
void kp_fused(const float* __restrict__ hid,  const float* __restrict__ fkp,
              const float* __restrict__ w1ld, const float* __restrict__ b1ld,
              const float* __restrict__ gld,  const float* __restrict__ btld,
              const float* __restrict__ w2ld, const float* __restrict__ b2ld,
              const float* __restrict__ w1sd, const float* __restrict__ b1sd,
              const float* __restrict__ gsd,  const float* __restrict__ btsd,
              const float* __restrict__ w2sd, const float* __restrict__ b2sd,
              const int* __restrict__ ctx,
              float* __restrict__ out, float* __restrict__ ws)
{
    __shared__ float hs[R_][H_];        // 64 KB: post-LN hidden; hs[8] head doubles as LN aux
    __shared__ float xs[R_][E_];        // 16 KB: staged input rows
    // total 81920 B exactly -> 2 blocks/CU (16 waves/CU)

    const int tid = threadIdx.x;
    const int g0  = blockIdx.x * R_;
    const int kp0 = ctx[0] - 1;

    // ---- stage x rows into LDS (coalesced): thread t -> row t>>5, floats (t&31)*8 .. +7
    {
        const int r   = tid >> 5;          // 0..15
        const int off = (tid & 31) * 8;
        const int g = g0 + r;
        const int b = g / T_;
        const int t = g - b * T_;
        const float* src = hid + (size_t)(b * S_ + kp0 + t) * E_ + off;
        float4 v0 = *(const float4*)(src);
        float4 v1 = *(const float4*)(src + 4);
        *(float4*)&xs[r][off]     = v0;
        *(float4*)&xs[r][off + 4] = v1;
    }
    __syncthreads();

    decoder_phase<12>(xs, w1ld, b1ld, gld, btld, w2ld, b2ld,
                      hs, &hs[8][0], out + OFF_LOGITS, g0, tid);
    decoder_phase<6>(xs, w1sd, b1sd, gsd, btsd, w2sd, b2sd,
                     hs, &hs[8][0], out + OFF_SCORES, g0, tid);

    // ---- per-row loss epilogue: lane 0 of each wave handles its 2 rows ----
    // re-reads the logits/scores THIS THREAD wrote (program-order visibility)
    {
        const int wave = tid >> 6;
        const int lane = tid & 63;
        if (lane == 0) {
#pragma unroll
            for (int rr = 0; rr < 2; ++rr) {
                const int g = g0 + wave*2 + rr;
                const int b = g / T_;
                const int t = g - b * T_;
                const float y0 = fkp[b*(T_*2) + t*2 + 0];
                const float y1 = fkp[b*(T_*2) + t*2 + 1];

                float lo[12];
#pragma unroll
                for (int n = 0; n < 12; ++n) lo[n] = out[OFF_LOGITS + (size_t)g*12 + n];
                float sc[KK_];
#pragma unroll
                for (int n = 0; n < KK_; ++n) sc[n] = out[OFF_SCORES + (size_t)g*6 + n];

                float best = 1e30f; int am = 0;
#pragma unroll
                for (int k = 0; k < KK_; ++k) {
                    float dx = lo[2*k + 0] - y0;
                    float dy = lo[2*k + 1] - y1;
                    float L = dx*dx + dy*dy;
                    if (L < best) { best = L; am = k; }  // strict <: first-min like jnp.argmin
                }

                // softmax(scores) then log_softmax(softmax) (faithful double softmax)
                float m = -1e30f;
#pragma unroll
                for (int k = 0; k < KK_; ++k) m = fmaxf(m, sc[k]);
                float e[KK_]; float ssum = 0.f;
#pragma unroll
                for (int k = 0; k < KK_; ++k) { e[k] = expf(sc[k] - m); ssum += e[k]; }
                const float inv = 1.0f / ssum;
                float lse = 0.f, sm_am = 0.f;
#pragma unroll
                for (int k = 0; k < KK_; ++k) {
                    float smk = e[k] * inv;
                    lse += expf(smk);
                    if (k == am) sm_am = smk;
                }
                const float ce = logf(lse) - sm_am;   // -(sm[am] - logsumexp(sm))

                // compile-time-indexed select of the winning logit pair (no scratch)
                float sx = 0.f, sy = 0.f;
#pragma unroll
                for (int k = 0; k < KK_; ++k)
                    if (k == am) { sx = lo[2*k + 0]; sy = lo[2*k + 1]; }

                out[OFF_SEL + g*2 + 0] = sx;
                out[OFF_SEL + g*2 + 1] = sy;

                atomicAdd(&ws[t],       best);  // sum over B of min_loss, per t
                atomicAdd(&ws[T_ + t],  ce);    // sum over B of ce, per t
            }
        }
    }
}

__global__ void kp_finalize(const float* __restrict__ ws, float* __restrict__ out)
{
    if (threadIdx.x == 0 && blockIdx.x == 0) {
        const float wts[T_] = {1e-4f, 1e-3f, 1e-2f, 1e-1f, 1.0f}; // 0.1^(4-t)
        float s = 0.f;
#pragma unroll
        for (int t = 0; t < T_; ++t) {
            float ml = ws[t]      * (1.0f / B_);
            float ce = ws[T_ + t] * (1.0f / B_);
            float l  = ml * wts[t] + ce;
            out[OFF_LPK + t] = l;
            s += l;
        }
        out[0] = s * (1.0f / T_);   // kp_loss (rescale = 1.0)
    }
}

extern "C" void kernel_launch(void* const* d_in, const int* in_sizes, int n_in,
                              void* d_out, int out_size, void* d_ws, size_t ws_size,
                              hipStream_t stream)
{
    const float* hid  = (const float*)d_in[0];
    const float* fkp  = (const float*)d_in[1];
    const float* w1ld = (const float*)d_in[2];
    const float* b1ld = (const float*)d_in[3];
    const float* gld  = (const float*)d_in[4];
    const float* btld = (const float*)d_in[5];
    const float* w2ld = (const float*)d_in[6];
    const float* b2ld = (const float*)d_in[7];
    const float* w1sd = (const float*)d_in[8];
    const float* b1sd = (const float*)d_in[9];
    const float* gsd  = (const float*)d_in[10];
    const float* btsd = (const float*)d_in[11];
    const float* w2sd = (const float*)d_in[12];
    const float* b2sd = (const float*)d_in[13];
    const int*   ctx  = (const int*)d_in[14];
    float* out = (float*)d_out;
    float* ws  = (float*)d_ws;

    // zero the 10 loss accumulators (ws is poisoned 0xAA before every launch)
    hipMemsetAsync(ws, 0, 2 * T_ * sizeof(float), stream);

    kp_fused<<<NBLK, NT_, 0, stream>>>(hid, fkp,
                                       w1ld, b1ld, gld, btld, w2ld, b2ld,
                                       w1sd, b1sd, gsd, btsd, w2sd, b2sd,
                                       ctx, out, ws);
    kp_finalize<<<1, 64, 0, stream>>>(ws, out);
}

// Round 7
// 704.163 us; speedup vs baseline: 1.0559x; 1.0559x over previous
//
#include <hip/hip_runtime.h>
#include <math.h>

#define B_    2048
#define S_    134
#define E_    256
#define H_    1024
#define T_    5
#define KK_   6
#define NROWS (B_*T_)          // 10240
#define R_    8                // rows per block
#define NBLK  (NROWS/R_)       // 1280

// output layout (flat concat in return order)
#define OFF_LOGITS 1
#define OFF_SCORES (OFF_LOGITS + NROWS*12)   // 122881
#define OFF_SEL    (OFF_SCORES + NROWS*6)    // 184321
#define OFF_LPK    (OFF_SEL + NROWS*2)       // 204801

// load one w2 row (NOUT floats) with the widest aligned vector type:
// NOUT=12 -> rows are 48 B, 16B-aligned -> 3x float4
// NOUT=6  -> rows are 24 B,  8B-aligned -> 3x float2
template<int NOUT>
__device__ __forceinline__ void load_w2row(const float* __restrict__ p, float (&w)[NOUT])
{
    if constexpr (NOUT == 12) {
        float4 a = *(const float4*)(p);
        float4 b = *(const float4*)(p + 4);
        float4 c = *(const float4*)(p + 8);
        w[0]=a.x; w[1]=a.y; w[2]=a.z; w[3]=a.w;
        w[4]=b.x; w[5]=b.y; w[6]=b.z; w[7]=b.w;
        w[8]=c.x; w[9]=c.y; w[10]=c.z; w[11]=c.w;
    } else {
        float2 a = *(const float2*)(p);
        float2 b = *(const float2*)(p + 2);
        float2 c = *(const float2*)(p + 4);
        w[0]=a.x; w[1]=a.y; w[2]=b.x; w[3]=b.y; w[4]=c.x; w[5]=c.y;
    }
}

// One decoder phase: GEMM1 (x@w1+b1) -> LayerNorm -> ReLU -> GEMM2 ([x,h]@w2+b2)
// Round-5 proven envelope (84 VGPR, LDS 40960 = 4 blocks/CU, launch_bounds(256,3)).
// GEMM2 restructured: lane owns j = chunk*256 + 4*lane ->
//   - xs/hs reads are contiguous float4 LDS reads (conflict-free, 10 ds_read_b128
//     instead of 40 stride-80B ds_read_b32)
//   - w2 rows load as float4/float2 (60 vector loads instead of 240 scalar
//     gathers; each wave reads the 61 KB w2 region once, L1-resident after)
// Spill history: launch_bounds(256,4) makes the allocator target the 64-VGPR
// bucket and spill (rounds 1/4, measured). Keep (256,3).
template<int NOUT>
__device__ __forceinline__ void decoder_phase(
    const float (*xs)[E_],
    const float* __restrict__ w1, const float* __restrict__ b1,
    const float* __restrict__ ga, const float* __restrict__ be,
    const float* __restrict__ w2, const float* __restrict__ b2,
    float (*hs)[H_], float* aux,            // aux == &hs[0][0], 64 floats
    float* __restrict__ gout, int g0, int tid)
{
    const int wave = tid >> 6;
    const int lane = tid & 63;
    const int j0   = tid * 4;

    // ---- GEMM1: acc[r][c] = xs[r][:] . w1[:, j0+c] ----
    float acc[R_][4];
#pragma unroll
    for (int r = 0; r < R_; ++r) {
        acc[r][0] = 0.f; acc[r][1] = 0.f; acc[r][2] = 0.f; acc[r][3] = 0.f;
    }

    for (int k0 = 0; k0 < E_; k0 += 8) {
        // batch 8 coalesced float4 loads of w1 (8 VMEM in flight)
        float4 w[8];
#pragma unroll
        for (int kk = 0; kk < 8; ++kk)
            w[kk] = *(const float4*)(w1 + (size_t)(k0 + kk)*H_ + j0);
#pragma unroll
        for (int r = 0; r < R_; ++r) {
            float4 xa = *(const float4*)&xs[r][k0];     // wave-uniform -> LDS broadcast
            float4 xb = *(const float4*)&xs[r][k0+4];
            acc[r][0] += xa.x*w[0].x; acc[r][1] += xa.x*w[0].y; acc[r][2] += xa.x*w[0].z; acc[r][3] += xa.x*w[0].w;
            acc[r][0] += xa.y*w[1].x; acc[r][1] += xa.y*w[1].y; acc[r][2] += xa.y*w[1].z; acc[r][3] += xa.y*w[1].w;
            acc[r][0] += xa.z*w[2].x; acc[r][1] += xa.z*w[2].y; acc[r][2] += xa.z*w[2].z; acc[r][3] += xa.z*w[2].w;
            acc[r][0] += xa.w*w[3].x; acc[r][1] += xa.w*w[3].y; acc[r][2] += xa.w*w[3].z; acc[r][3] += xa.w*w[3].w;
            acc[r][0] += xb.x*w[4].x; acc[r][1] += xb.x*w[4].y; acc[r][2] += xb.x*w[4].z; acc[r][3] += xb.x*w[4].w;
            acc[r][0] += xb.y*w[5].x; acc[r][1] += xb.y*w[5].y; acc[r][2] += xb.y*w[5].z; acc[r][3] += xb.y*w[5].w;
            acc[r][0] += xb.z*w[6].x; acc[r][1] += xb.z*w[6].y; acc[r][2] += xb.z*w[6].z; acc[r][3] += xb.z*w[6].w;
            acc[r][0] += xb.w*w[7].x; acc[r][1] += xb.w*w[7].y; acc[r][2] += xb.w*w[7].z; acc[r][3] += xb.w*w[7].w;
        }
    }

    // bias
    {
        float4 bv = *(const float4*)(b1 + j0);
#pragma unroll
        for (int r = 0; r < R_; ++r) {
            acc[r][0] += bv.x; acc[r][1] += bv.y; acc[r][2] += bv.z; acc[r][3] += bv.w;
        }
    }

    // ---- LayerNorm stats: per-row sum / sumsq across 1024 cols ----
    // lane0 of each wave writes its partials into aux (= hs[0][0..63], dead here)
#pragma unroll
    for (int r = 0; r < R_; ++r) {
        float s  = acc[r][0] + acc[r][1] + acc[r][2] + acc[r][3];
        float ss = acc[r][0]*acc[r][0] + acc[r][1]*acc[r][1]
                 + acc[r][2]*acc[r][2] + acc[r][3]*acc[r][3];
#pragma unroll
        for (int off = 32; off > 0; off >>= 1) {
            s  += __shfl_xor(s,  off, 64);
            ss += __shfl_xor(ss, off, 64);
        }
        if (lane == 0) { aux[r*8 + wave*2 + 0] = s; aux[r*8 + wave*2 + 1] = ss; }
    }
    __syncthreads();

    // every thread folds the 4 wave-partials per row into mu/rs registers
    float mu[R_], rs[R_];
#pragma unroll
    for (int r = 0; r < R_; ++r) {
        float s  = aux[r*8+0] + aux[r*8+2] + aux[r*8+4] + aux[r*8+6];
        float ss = aux[r*8+1] + aux[r*8+3] + aux[r*8+5] + aux[r*8+7];
        float m  = s * (1.0f / H_);
        float var = ss * (1.0f / H_) - m * m;
        mu[r] = m;
        rs[r] = rsqrtf(var + 1e-5f);
    }
    __syncthreads();   // all aux reads complete before hs writes clobber aux region

    // ---- LN apply + ReLU -> hs ----
    {
        float4 gv = *(const float4*)(ga + j0);
        float4 bv = *(const float4*)(be + j0);
#pragma unroll
        for (int r = 0; r < R_; ++r) {
            float4 hv;
            hv.x = gv.x * ((acc[r][0] - mu[r]) * rs[r]) + bv.x;
            hv.y = gv.y * ((acc[r][1] - mu[r]) * rs[r]) + bv.y;
            hv.z = gv.z * ((acc[r][2] - mu[r]) * rs[r]) + bv.z;
            hv.w = gv.w * ((acc[r][3] - mu[r]) * rs[r]) + bv.w;
            hv.x = hv.x > 0.f ? hv.x : 0.f;
            hv.y = hv.y > 0.f ? hv.y : 0.f;
            hv.z = hv.z > 0.f ? hv.z : 0.f;
            hv.w = hv.w > 0.f ? hv.w : 0.f;
            *(float4*)&hs[r][j0] = hv;
        }
    }
    __syncthreads();

    // ---- GEMM2: out[r][n] = [x,h][r] . w2[:, n] + b2[n] ----
    // wave handles rows wave*2 .. wave*2+1; lane owns j = chunk*256 + 4*lane
    float p[2][NOUT];
#pragma unroll
    for (int rr = 0; rr < 2; ++rr)
#pragma unroll
        for (int n = 0; n < NOUT; ++n) p[rr][n] = 0.f;

    const int r0 = wave*2;
    const int j4 = lane*4;

    // x-part: j in [0,256), lane owns 4 contiguous cols -> contiguous wave read
    {
        float4 xv0 = *(const float4*)&xs[r0+0][j4];
        float4 xv1 = *(const float4*)&xs[r0+1][j4];
#pragma unroll
        for (int c = 0; c < 4; ++c) {
            float w2r[NOUT];
            load_w2row<NOUT>(w2 + (size_t)(j4 + c)*NOUT, w2r);
            const float a0 = (&xv0.x)[c];
            const float a1 = (&xv1.x)[c];
#pragma unroll
            for (int n = 0; n < NOUT; ++n) {
                p[0][n] += a0 * w2r[n];
                p[1][n] += a1 * w2r[n];
            }
        }
    }
    // h-part: j in [0,1024) over 4 chunks of 256; lane owns 4 contiguous cols each
#pragma unroll
    for (int chunk = 0; chunk < 4; ++chunk) {
        const int jh = chunk*256 + j4;
        float4 hv0 = *(const float4*)&hs[r0+0][jh];
        float4 hv1 = *(const float4*)&hs[r0+1][jh];
#pragma unroll
        for (int c = 0; c < 4; ++c) {
            float w2r[NOUT];
            load_w2row<NOUT>(w2 + (size_t)(E_ + jh + c)*NOUT, w2r);
            const float a0 = (&hv0.x)[c];
            const float a1 = (&hv1.x)[c];
#pragma unroll
            for (int n = 0; n < NOUT; ++n) {
                p[0][n] += a0 * w2r[n];
                p[1][n] += a1 * w2r[n];
            }
        }
    }

    // butterfly reduce across the wave
#pragma unroll
    for (int rr = 0; rr < 2; ++rr)
#pragma unroll
        for (int n = 0; n < NOUT; ++n)
#pragma unroll
            for (int off = 32; off > 0; off >>= 1)
                p[rr][n] += __shfl_xor(p[rr][n], off, 64);

    if (lane == 0) {
#pragma unroll
        for (int rr = 0; rr < 2; ++rr) {
            const int g = g0 + r0 + rr;
#pragma unroll
            for (int n = 0; n < NOUT; ++n)
                gout[(size_t)g*NOUT + n] = p[rr][n] + b2[n];
        }
    }
    __syncthreads();   // next phase's aux write must wait for all GEMM2 hs reads
}

__global__ __launch_bounds__(256, 3)
void kp_fused(const float* __restrict__ hid,  const float* __restrict__ fkp,
              const float* __restrict__ w1ld, const float* __restrict__ b1ld,
              const float* __restrict__ gld,  const float* __restrict__ btld,
              const float* __restrict__ w2ld, const float* __restrict__ b2ld,
              const float* __restrict__ w1sd, const float* __restrict__ b1sd,
              const float* __restrict__ gsd,  const float* __restrict__ btsd,
              const float* __restrict__ w2sd, const float* __restrict__ b2sd,
              const int* __restrict__ ctx,
              float* __restrict__ out, float* __restrict__ ws)
{
    __shared__ float hs[R_][H_];        // 32 KB: post-LN hidden; head doubles as LN aux
    __shared__ float xs[R_][E_];        // 8 KB: staged input rows
    // total 40960 B exactly -> 4 blocks/CU

    const int tid = threadIdx.x;
    const int g0  = blockIdx.x * R_;
    const int kp0 = ctx[0] - 1;

    // ---- stage x rows into LDS (coalesced): thread t -> row t>>5, floats (t&31)*8 .. +7
    {
        const int r   = tid >> 5;
        const int off = (tid & 31) * 8;
        const int g = g0 + r;
        const int b = g / T_;
        const int t = g - b * T_;
        const float* src = hid + (size_t)(b * S_ + kp0 + t) * E_ + off;
        float4 v0 = *(const float4*)(src);
        float4 v1 = *(const float4*)(src + 4);
        *(float4*)&xs[r][off]     = v0;
        *(float4*)&xs[r][off + 4] = v1;
    }
    __syncthreads();

    decoder_phase<12>(xs, w1ld, b1ld, gld, btld, w2ld, b2ld,
                      hs, &hs[0][0], out + OFF_LOGITS, g0, tid);
    decoder_phase<6>(xs, w1sd, b1sd, gsd, btsd, w2sd, b2sd,
                     hs, &hs[0][0], out + OFF_SCORES, g0, tid);

    // ---- per-row loss epilogue: lane 0 of each wave handles its 2 rows ----
    // re-reads the logits/scores THIS THREAD wrote (program-order visibility)
    {
        const int wave = tid >> 6;
        const int lane = tid & 63;
        if (lane == 0) {
#pragma unroll
            for (int rr = 0; rr < 2; ++rr) {
                const int g = g0 + wave*2 + rr;
                const int b = g / T_;
                const int t = g - b * T_;
                const float y0 = fkp[b*(T_*2) + t*2 + 0];
                const float y1 = fkp[b*(T_*2) + t*2 + 1];

                float lo[12];
#pragma unroll
                for (int n = 0; n < 12; ++n) lo[n] = out[OFF_LOGITS + (size_t)g*12 + n];
                float sc[KK_];
#pragma unroll
                for (int n = 0; n < KK_; ++n) sc[n] = out[OFF_SCORES + (size_t)g*6 + n];

                float best = 1e30f; int am = 0;
#pragma unroll
                for (int k = 0; k < KK_; ++k) {
                    float dx = lo[2*k + 0] - y0;
                    float dy = lo[2*k + 1] - y1;
                    float L = dx*dx + dy*dy;
                    if (L < best) { best = L; am = k; }  // strict <: first-min like jnp.argmin
                }

                // softmax(scores) then log_softmax(softmax) (faithful double softmax)
                float m = -1e30f;
#pragma unroll
                for (int k = 0; k < KK_; ++k) m = fmaxf(m, sc[k]);
                float e[KK_]; float ssum = 0.f;
#pragma unroll
                for (int k = 0; k < KK_; ++k) { e[k] = expf(sc[k] - m); ssum += e[k]; }
                const float inv = 1.0f / ssum;
                float lse = 0.f, sm_am = 0.f;
#pragma unroll
                for (int k = 0; k < KK_; ++k) {
                    float smk = e[k] * inv;
                    lse += expf(smk);
                    if (k == am) sm_am = smk;
                }
                const float ce = logf(lse) - sm_am;   // -(sm[am] - logsumexp(sm))

                // compile-time-indexed select of the winning logit pair (no scratch)
                float sx = 0.f, sy = 0.f;
#pragma unroll
                for (int k = 0; k < KK_; ++k)
                    if (k == am) { sx = lo[2*k + 0]; sy = lo[2*k + 1]; }

                out[OFF_SEL + g*2 + 0] = sx;
                out[OFF_SEL + g*2 + 1] = sy;

                atomicAdd(&ws[t],       best);  // sum over B of min_loss, per t
                atomicAdd(&ws[T_ + t],  ce);    // sum over B of ce, per t
            }
        }
    }
}

__global__ void kp_finalize(const float* __restrict__ ws, float* __restrict__ out)
{
    if (threadIdx.x == 0 && blockIdx.x == 0) {
        const float wts[T_] = {1e-4f, 1e-3f, 1e-2f, 1e-1f, 1.0f}; // 0.1^(4-t)
        float s = 0.f;
#pragma unroll
        for (int t = 0; t < T_; ++t) {
            float ml = ws[t]      * (1.0f / B_);
            float ce = ws[T_ + t] * (1.0f / B_);
            float l  = ml * wts[t] + ce;
            out[OFF_LPK + t] = l;
            s += l;
        }
        out[0] = s * (1.0f / T_);   // kp_loss (rescale = 1.0)
    }
}

extern "C" void kernel_launch(void* const* d_in, const int* in_sizes, int n_in,
                              void* d_out, int out_size, void* d_ws, size_t ws_size,
                              hipStream_t stream)
{
    const float* hid  = (const float*)d_in[0];
    const float* fkp  = (const float*)d_in[1];
    const float* w1ld = (const float*)d_in[2];
    const float* b1ld = (const float*)d_in[3];
    const float* gld  = (const float*)d_in[4];
    const float* btld = (const float*)d_in[5];
    const float* w2ld = (const float*)d_in[6];
    const float* b2ld = (const float*)d_in[7];
    const float* w1sd = (const float*)d_in[8];
    const float* b1sd = (const float*)d_in[9];
    const float* gsd  = (const float*)d_in[10];
    const float* btsd = (const float*)d_in[11];
    const float* w2sd = (const float*)d_in[12];
    const float* b2sd = (const float*)d_in[13];
    const int*   ctx  = (const int*)d_in[14];
    float* out = (float*)d_out;
    float* ws  = (float*)d_ws;

    // zero the 10 loss accumulators (ws is poisoned 0xAA before every launch)
    hipMemsetAsync(ws, 0, 2 * T_ * sizeof(float), stream);

    kp_fused<<<NBLK, 256, 0, stream>>>(hid, fkp,
                                       w1ld, b1ld, gld, btld, w2ld, b2ld,
                                       w1sd, b1sd, gsd, btsd, w2sd, b2sd,
                                       ctx, out, ws);
    kp_finalize<<<1, 64, 0, stream>>>(ws, out);
}

// Round 8
// 694.249 us; speedup vs baseline: 1.0710x; 1.0143x over previous
//
#include <hip/hip_runtime.h>
#include <math.h>

#define B_    2048
#define S_    134
#define E_    256
#define H_    1024
#define T_    5
#define KK_   6
#define NROWS (B_*T_)          // 10240
#define R_    8                // rows per block
#define NBLK  (NROWS/R_)       // 1280

// output layout (flat concat in return order)
#define OFF_LOGITS 1
#define OFF_SCORES (OFF_LOGITS + NROWS*12)   // 122881
#define OFF_SEL    (OFF_SCORES + NROWS*6)    // 184321
#define OFF_LPK    (OFF_SEL + NROWS*2)       // 204801

__device__ __forceinline__ void fma4(float (&a)[4], float s, const float4& w)
{
    a[0] += s*w.x; a[1] += s*w.y; a[2] += s*w.z; a[3] += s*w.w;
}

// load one w2 row (NOUT floats) with the widest aligned vector type
template<int NOUT>
__device__ __forceinline__ void load_w2row(const float* __restrict__ p, float (&w)[NOUT])
{
    if constexpr (NOUT == 12) {
        float4 a = *(const float4*)(p);
        float4 b = *(const float4*)(p + 4);
        float4 c = *(const float4*)(p + 8);
        w[0]=a.x; w[1]=a.y; w[2]=a.z; w[3]=a.w;
        w[4]=b.x; w[5]=b.y; w[6]=b.z; w[7]=b.w;
        w[8]=c.x; w[9]=c.y; w[10]=c.z; w[11]=c.w;
    } else {
        float2 a = *(const float2*)(p);
        float2 b = *(const float2*)(p + 2);
        float2 c = *(const float2*)(p + 4);
        w[0]=a.x; w[1]=a.y; w[2]=b.x; w[3]=b.y; w[4]=c.x; w[5]=c.y;
    }
}

// GEMM2: out[r][n] = [x,h][r] . w2[:, n] + b2[n]  (round-7 vectorized form)
template<int NOUT>
__device__ __forceinline__ void gemm2_phase(
    const float (*xs)[E_], const float (*hs)[H_],
    const float* __restrict__ w2, const float* __restrict__ b2,
    float* __restrict__ gout, int g0, int wave, int lane)
{
    float p[2][NOUT];
#pragma unroll
    for (int rr = 0; rr < 2; ++rr)
#pragma unroll
        for (int n = 0; n < NOUT; ++n) p[rr][n] = 0.f;

    const int r0 = wave*2;
    const int j4 = lane*4;

    // x-part: lane owns 4 contiguous cols -> contiguous wave read
    {
        float4 xv0 = *(const float4*)&xs[r0+0][j4];
        float4 xv1 = *(const float4*)&xs[r0+1][j4];
#pragma unroll
        for (int c = 0; c < 4; ++c) {
            float w2r[NOUT];
            load_w2row<NOUT>(w2 + (size_t)(j4 + c)*NOUT, w2r);
            const float a0 = (&xv0.x)[c];
            const float a1 = (&xv1.x)[c];
#pragma unroll
            for (int n = 0; n < NOUT; ++n) {
                p[0][n] += a0 * w2r[n];
                p[1][n] += a1 * w2r[n];
            }
        }
    }
    // h-part: 4 chunks of 256 cols
#pragma unroll
    for (int chunk = 0; chunk < 4; ++chunk) {
        const int jh = chunk*256 + j4;
        float4 hv0 = *(const float4*)&hs[r0+0][jh];
        float4 hv1 = *(const float4*)&hs[r0+1][jh];
#pragma unroll
        for (int c = 0; c < 4; ++c) {
            float w2r[NOUT];
            load_w2row<NOUT>(w2 + (size_t)(E_ + jh + c)*NOUT, w2r);
            const float a0 = (&hv0.x)[c];
            const float a1 = (&hv1.x)[c];
#pragma unroll
            for (int n = 0; n < NOUT; ++n) {
                p[0][n] += a0 * w2r[n];
                p[1][n] += a1 * w2r[n];
            }
        }
    }

    // butterfly reduce across the wave
#pragma unroll
    for (int rr = 0; rr < 2; ++rr)
#pragma unroll
        for (int n = 0; n < NOUT; ++n)
#pragma unroll
            for (int off = 32; off > 0; off >>= 1)
                p[rr][n] += __shfl_xor(p[rr][n], off, 64);

    if (lane == 0) {
#pragma unroll
        for (int rr = 0; rr < 2; ++rr) {
            const int g = g0 + r0 + rr;
#pragma unroll
            for (int n = 0; n < NOUT; ++n)
                gout[(size_t)g*NOUT + n] = p[rr][n] + b2[n];
        }
    }
}

// Fused dual-decoder kernel. The two decoders (ld, sd) share input rows xs,
// so their GEMM1s are FUSED into one k-loop: per iteration, 16 w1 loads in
// flight (8 ld + 8 sd) feed 512 FMAs -> per-wave load-stall fraction ~halves
// vs the sequential-phase version (measured 33% of VALU roofline, latency-
// bound, rounds 5/7). xs LDS reads are shared between both accumulator sets.
// LN reduction for BOTH phases overlays hs[0][0..127] (dead region).
// LDS = 40960 B exactly -> 4 blocks/CU.
// Spill history: launch_bounds(256,4) => allocator targets the 64-VGPR bucket
// and spills (rounds 1/4, measured). Keep (256,3) (cap 168; landed 84 clean
// in rounds 0/5/7; expect ~140-160 here).
__global__ __launch_bounds__(256, 3)
void kp_fused(const float* __restrict__ hid,  const float* __restrict__ fkp,
              const float* __restrict__ w1ld, const float* __restrict__ b1ld,
              const float* __restrict__ gld,  const float* __restrict__ btld,
              const float* __restrict__ w2ld, const float* __restrict__ b2ld,
              const float* __restrict__ w1sd, const float* __restrict__ b1sd,
              const float* __restrict__ gsd,  const float* __restrict__ btsd,
              const float* __restrict__ w2sd, const float* __restrict__ b2sd,
              const int* __restrict__ ctx,
              float* __restrict__ out, float* __restrict__ ws)
{
    __shared__ float hs[R_][H_];        // 32 KB: post-LN hidden; head doubles as LN aux
    __shared__ float xs[R_][E_];        // 8 KB: staged input rows
    // total 40960 B exactly -> 4 blocks/CU

    const int tid = threadIdx.x;
    const int g0  = blockIdx.x * R_;
    const int kp0 = ctx[0] - 1;
    const int wave = tid >> 6;
    const int lane = tid & 63;
    const int j0   = tid * 4;
    float* aux = &hs[0][0];             // 128 floats of LN partials (dead region)

    // ---- stage x rows into LDS (coalesced) ----
    {
        const int r   = tid >> 5;
        const int off = (tid & 31) * 8;
        const int g = g0 + r;
        const int b = g / T_;
        const int t = g - b * T_;
        const float* src = hid + (size_t)(b * S_ + kp0 + t) * E_ + off;
        float4 v0 = *(const float4*)(src);
        float4 v1 = *(const float4*)(src + 4);
        *(float4*)&xs[r][off]     = v0;
        *(float4*)&xs[r][off + 4] = v1;
    }
    __syncthreads();

    // ---- FUSED GEMM1: acc1 = xs@w1ld, acc2 = xs@w1sd ----
    float acc1[R_][4], acc2[R_][4];
#pragma unroll
    for (int r = 0; r < R_; ++r) {
        acc1[r][0]=0.f; acc1[r][1]=0.f; acc1[r][2]=0.f; acc1[r][3]=0.f;
        acc2[r][0]=0.f; acc2[r][1]=0.f; acc2[r][2]=0.f; acc2[r][3]=0.f;
    }

    for (int k0 = 0; k0 < E_; k0 += 8) {
        float4 wa[8], wb[8];                       // 16 VMEM loads in flight
#pragma unroll
        for (int kk = 0; kk < 8; ++kk)
            wa[kk] = *(const float4*)(w1ld + (size_t)(k0 + kk)*H_ + j0);
#pragma unroll
        for (int kk = 0; kk < 8; ++kk)
            wb[kk] = *(const float4*)(w1sd + (size_t)(k0 + kk)*H_ + j0);
#pragma unroll
        for (int r = 0; r < R_; ++r) {
            float4 xa = *(const float4*)&xs[r][k0];      // shared by both streams
            float4 xb = *(const float4*)&xs[r][k0+4];
            fma4(acc1[r], xa.x, wa[0]); fma4(acc1[r], xa.y, wa[1]);
            fma4(acc1[r], xa.z, wa[2]); fma4(acc1[r], xa.w, wa[3]);
            fma4(acc1[r], xb.x, wa[4]); fma4(acc1[r], xb.y, wa[5]);
            fma4(acc1[r], xb.z, wa[6]); fma4(acc1[r], xb.w, wa[7]);
            fma4(acc2[r], xa.x, wb[0]); fma4(acc2[r], xa.y, wb[1]);
            fma4(acc2[r], xa.z, wb[2]); fma4(acc2[r], xa.w, wb[3]);
            fma4(acc2[r], xb.x, wb[4]); fma4(acc2[r], xb.y, wb[5]);
            fma4(acc2[r], xb.z, wb[6]); fma4(acc2[r], xb.w, wb[7]);
        }
    }

    // biases
    {
        float4 bv1 = *(const float4*)(b1ld + j0);
        float4 bv2 = *(const float4*)(b1sd + j0);
#pragma unroll
        for (int r = 0; r < R_; ++r) {
            acc1[r][0]+=bv1.x; acc1[r][1]+=bv1.y; acc1[r][2]+=bv1.z; acc1[r][3]+=bv1.w;
            acc2[r][0]+=bv2.x; acc2[r][1]+=bv2.y; acc2[r][2]+=bv2.z; acc2[r][3]+=bv2.w;
        }
    }

    // ---- LayerNorm stats for BOTH phases ----
#pragma unroll
    for (int r = 0; r < R_; ++r) {
        float s1  = acc1[r][0] + acc1[r][1] + acc1[r][2] + acc1[r][3];
        float ss1 = acc1[r][0]*acc1[r][0] + acc1[r][1]*acc1[r][1]
                  + acc1[r][2]*acc1[r][2] + acc1[r][3]*acc1[r][3];
        float s2  = acc2[r][0] + acc2[r][1] + acc2[r][2] + acc2[r][3];
        float ss2 = acc2[r][0]*acc2[r][0] + acc2[r][1]*acc2[r][1]
                  + acc2[r][2]*acc2[r][2] + acc2[r][3]*acc2[r][3];
#pragma unroll
        for (int off = 32; off > 0; off >>= 1) {
            s1  += __shfl_xor(s1,  off, 64);
            ss1 += __shfl_xor(ss1, off, 64);
            s2  += __shfl_xor(s2,  off, 64);
            ss2 += __shfl_xor(ss2, off, 64);
        }
        if (lane == 0) {
            aux[r*16 + wave*4 + 0] = s1;
            aux[r*16 + wave*4 + 1] = ss1;
            aux[r*16 + wave*4 + 2] = s2;
            aux[r*16 + wave*4 + 3] = ss2;
        }
    }
    __syncthreads();

    // fold the 4 wave-partials per row for both phases (all in registers)
    float mu1[R_], rs1v[R_], mu2[R_], rs2v[R_];
#pragma unroll
    for (int r = 0; r < R_; ++r) {
        float s1  = aux[r*16+0] + aux[r*16+4] + aux[r*16+8]  + aux[r*16+12];
        float ss1 = aux[r*16+1] + aux[r*16+5] + aux[r*16+9]  + aux[r*16+13];
        float s2  = aux[r*16+2] + aux[r*16+6] + aux[r*16+10] + aux[r*16+14];
        float ss2 = aux[r*16+3] + aux[r*16+7] + aux[r*16+11] + aux[r*16+15];
        float m1 = s1 * (1.0f / H_);
        float m2 = s2 * (1.0f / H_);
        mu1[r] = m1;  rs1v[r] = rsqrtf(ss1 * (1.0f / H_) - m1*m1 + 1e-5f);
        mu2[r] = m2;  rs2v[r] = rsqrtf(ss2 * (1.0f / H_) - m2*m2 + 1e-5f);
    }
    __syncthreads();   // all aux reads complete before hs writes clobber aux region

    // ---- phase 1 (ld): LN apply + ReLU -> hs ----
    {
        float4 gv = *(const float4*)(gld + j0);
        float4 bv = *(const float4*)(btld + j0);
#pragma unroll
        for (int r = 0; r < R_; ++r) {
            float4 hv;
            hv.x = gv.x * ((acc1[r][0] - mu1[r]) * rs1v[r]) + bv.x;
            hv.y = gv.y * ((acc1[r][1] - mu1[r]) * rs1v[r]) + bv.y;
            hv.z = gv.z * ((acc1[r][2] - mu1[r]) * rs1v[r]) + bv.z;
            hv.w = gv.w * ((acc1[r][3] - mu1[r]) * rs1v[r]) + bv.w;
            hv.x = hv.x > 0.f ? hv.x : 0.f;
            hv.y = hv.y > 0.f ? hv.y : 0.f;
            hv.z = hv.z > 0.f ? hv.z : 0.f;
            hv.w = hv.w > 0.f ? hv.w : 0.f;
            *(float4*)&hs[r][j0] = hv;
        }
    }
    __syncthreads();

    gemm2_phase<12>(xs, hs, w2ld, b2ld, out + OFF_LOGITS, g0, wave, lane);
    __syncthreads();   // all GEMM2-1 hs reads done before phase-2 apply clobbers

    // ---- phase 2 (sd): LN apply + ReLU -> hs ----
    {
        float4 gv = *(const float4*)(gsd + j0);
        float4 bv = *(const float4*)(btsd + j0);
#pragma unroll
        for (int r = 0; r < R_; ++r) {
            float4 hv;
            hv.x = gv.x * ((acc2[r][0] - mu2[r]) * rs2v[r]) + bv.x;
            hv.y = gv.y * ((acc2[r][1] - mu2[r]) * rs2v[r]) + bv.y;
            hv.z = gv.z * ((acc2[r][2] - mu2[r]) * rs2v[r]) + bv.z;
            hv.w = gv.w * ((acc2[r][3] - mu2[r]) * rs2v[r]) + bv.w;
            hv.x = hv.x > 0.f ? hv.x : 0.f;
            hv.y = hv.y > 0.f ? hv.y : 0.f;
            hv.z = hv.z > 0.f ? hv.z : 0.f;
            hv.w = hv.w > 0.f ? hv.w : 0.f;
            *(float4*)&hs[r][j0] = hv;
        }
    }
    __syncthreads();

    gemm2_phase<6>(xs, hs, w2sd, b2sd, out + OFF_SCORES, g0, wave, lane);

    // ---- per-row loss epilogue: lane 0 of each wave handles its 2 rows ----
    // re-reads the logits/scores THIS THREAD wrote (program-order visibility)
    if (lane == 0) {
#pragma unroll
        for (int rr = 0; rr < 2; ++rr) {
            const int g = g0 + wave*2 + rr;
            const int b = g / T_;
            const int t = g - b * T_;
            const float y0 = fkp[b*(T_*2) + t*2 + 0];
            const float y1 = fkp[b*(T_*2) + t*2 + 1];

            float lo[12];
#pragma unroll
            for (int n = 0; n < 12; ++n) lo[n] = out[OFF_LOGITS + (size_t)g*12 + n];
            float sc[KK_];
#pragma unroll
            for (int n = 0; n < KK_; ++n) sc[n] = out[OFF_SCORES + (size_t)g*6 + n];

            float best = 1e30f; int am = 0;
#pragma unroll
            for (int k = 0; k < KK_; ++k) {
                float dx = lo[2*k + 0] - y0;
                float dy = lo[2*k + 1] - y1;
                float L = dx*dx + dy*dy;
                if (L < best) { best = L; am = k; }  // strict <: first-min like jnp.argmin
            }

            // softmax(scores) then log_softmax(softmax) (faithful double softmax)
            float m = -1e30f;
#pragma unroll
            for (int k = 0; k < KK_; ++k) m = fmaxf(m, sc[k]);
            float e[KK_]; float ssum = 0.f;
#pragma unroll
            for (int k = 0; k < KK_; ++k) { e[k] = expf(sc[k] - m); ssum += e[k]; }
            const float inv = 1.0f / ssum;
            float lse = 0.f, sm_am = 0.f;
#pragma unroll
            for (int k = 0; k < KK_; ++k) {
                float smk = e[k] * inv;
                lse += expf(smk);
                if (k == am) sm_am = smk;
            }
            const float ce = logf(lse) - sm_am;   // -(sm[am] - logsumexp(sm))

            // compile-time-indexed select of the winning logit pair (no scratch)
            float sx = 0.f, sy = 0.f;
#pragma unroll
            for (int k = 0; k < KK_; ++k)
                if (k == am) { sx = lo[2*k + 0]; sy = lo[2*k + 1]; }

            out[OFF_SEL + g*2 + 0] = sx;
            out[OFF_SEL + g*2 + 1] = sy;

            atomicAdd(&ws[t],       best);  // sum over B of min_loss, per t
            atomicAdd(&ws[T_ + t],  ce);    // sum over B of ce, per t
        }
    }
}

__global__ void kp_finalize(const float* __restrict__ ws, float* __restrict__ out)
{
    if (threadIdx.x == 0 && blockIdx.x == 0) {
        const float wts[T_] = {1e-4f, 1e-3f, 1e-2f, 1e-1f, 1.0f}; // 0.1^(4-t)
        float s = 0.f;
#pragma unroll
        for (int t = 0; t < T_; ++t) {
            float ml = ws[t]      * (1.0f / B_);
            float ce = ws[T_ + t] * (1.0f / B_);
            float l  = ml * wts[t] + ce;
            out[OFF_LPK + t] = l;
            s += l;
        }
        out[0] = s * (1.0f / T_);   // kp_loss (rescale = 1.0)
    }
}

extern "C" void kernel_launch(void* const* d_in, const int* in_sizes, int n_in,
                              void* d_out, int out_size, void* d_ws, size_t ws_size,
                              hipStream_t stream)
{
    const float* hid  = (const float*)d_in[0];
    const float* fkp  = (const float*)d_in[1];
    const float* w1ld = (const float*)d_in[2];
    const float* b1ld = (const float*)d_in[3];
    const float* gld  = (const float*)d_in[4];
    const float* btld = (const float*)d_in[5];
    const float* w2ld = (const float*)d_in[6];
    const float* b2ld = (const float*)d_in[7];
    const float* w1sd = (const float*)d_in[8];
    const float* b1sd = (const float*)d_in[9];
    const float* gsd  = (const float*)d_in[10];
    const float* btsd = (const float*)d_in[11];
    const float* w2sd = (const float*)d_in[12];
    const float* b2sd = (const float*)d_in[13];
    const int*   ctx  = (const int*)d_in[14];
    float* out = (float*)d_out;
    float* ws  = (float*)d_ws;

    // zero the 10 loss accumulators (ws is poisoned 0xAA before every launch)
    hipMemsetAsync(ws, 0, 2 * T_ * sizeof(float), stream);

    kp_fused<<<NBLK, 256, 0, stream>>>(hid, fkp,
                                       w1ld, b1ld, gld, btld, w2ld, b2ld,
                                       w1sd, b1sd, gsd, btsd, w2sd, b2sd,
                                       ctx, out, ws);
    kp_finalize<<<1, 64, 0, stream>>>(ws, out);
}